// Round 1
// baseline (802.306 us; speedup 1.0000x reference)
//
#include <hip/hip_runtime.h>

// Elman RNN, B=262144, INPUT=32, HIDDEN=16, T=30, OUT=1, fp32.
// Round 1: one thread per batch row; weights via wave-uniform scalar loads
// (compiler -> s_load, SGPR operands in v_fma); fast tanh (exp2+rcp);
// output staged through LDS for coalesced stores.

#define T_STEPS   30
#define HIDDEN    16
#define INPUT_DIM 32
#define BLOCK     256

__device__ __forceinline__ float tanh_fast(float v) {
    // tanh(v) = 1 - 2/(exp(2v)+1); exp(2v) = exp2(v * 2*log2(e))
    float e = __builtin_amdgcn_exp2f(v * 2.8853900817779268f);
    float r = __builtin_amdgcn_rcpf(1.0f + e);
    // large +v: e=inf -> r=0 -> 1;  large -v: e=0 -> r=1 -> -1. Correct saturation.
    return fmaf(-2.0f, r, 1.0f);
}

__global__ __launch_bounds__(BLOCK, 4) void rnn_kernel(
    const float* __restrict__ x,     // [B, 32]
    const float* __restrict__ W_ih,  // [16, 32]
    const float* __restrict__ W_hh,  // [16, 16]
    const float* __restrict__ b_ih,  // [16]
    const float* __restrict__ b_hh,  // [16]
    const float* __restrict__ W_fc,  // [1, 16]
    const float* __restrict__ b_fc,  // [1]
    float* __restrict__ out)         // [B, 30]
{
    __shared__ float tmp[BLOCK * T_STEPS];  // flat idx r*30+t == linear out idx

    const int tid = threadIdx.x;
    const size_t row = (size_t)blockIdx.x * BLOCK + tid;

    // ---- load x row (8 x float4, 16B/lane) ----
    const float4* x4 = (const float4*)(x + row * INPUT_DIM);
    float xr[INPUT_DIM];
#pragma unroll
    for (int i = 0; i < INPUT_DIM / 4; ++i) {
        float4 v = x4[i];
        xr[4 * i + 0] = v.x;
        xr[4 * i + 1] = v.y;
        xr[4 * i + 2] = v.z;
        xr[4 * i + 3] = v.w;
    }

    // ---- xproj = x @ W_ih^T + b_ih + b_hh (weights uniform -> s_load) ----
    float xproj[HIDDEN];
#pragma unroll
    for (int j = 0; j < HIDDEN; ++j) {
        float acc = b_ih[j] + b_hh[j];
#pragma unroll
        for (int k = 0; k < INPUT_DIM; ++k)
            acc = fmaf(W_ih[j * INPUT_DIM + k], xr[k], acc);
        xproj[j] = acc;
    }

    // fc weights: uniform -> SGPRs
    float wfc[HIDDEN];
#pragma unroll
    for (int j = 0; j < HIDDEN; ++j) wfc[j] = W_fc[j];
    const float bfc = b_fc[0];

    float h[HIDDEN];
#pragma unroll
    for (int j = 0; j < HIDDEN; ++j) h[j] = 0.0f;

    // ---- recurrent loop (kept rolled over t: ~400 instr body, I$-friendly) ----
    for (int t = 0; t < T_STEPS; ++t) {
        float hn[HIDDEN];
#pragma unroll
        for (int j = 0; j < HIDDEN; ++j) {
            float acc = xproj[j];
#pragma unroll
            for (int k = 0; k < HIDDEN; ++k)
                acc = fmaf(W_hh[j * HIDDEN + k], h[k], acc);
            hn[j] = tanh_fast(acc);
        }
        float o = bfc;
#pragma unroll
        for (int j = 0; j < HIDDEN; ++j) {
            h[j] = hn[j];
            o = fmaf(hn[j], wfc[j], o);
        }
        tmp[tid * T_STEPS + t] = o;
    }

    __syncthreads();

    // ---- coalesced writeout: block's out region is contiguous [BLOCK*30] ----
    float* oblk = out + (size_t)blockIdx.x * (BLOCK * T_STEPS);
#pragma unroll
    for (int k = 0; k < T_STEPS; ++k) {
        int idx = tid + k * BLOCK;
        oblk[idx] = tmp[idx];
    }
}

extern "C" void kernel_launch(void* const* d_in, const int* in_sizes, int n_in,
                              void* d_out, int out_size, void* d_ws, size_t ws_size,
                              hipStream_t stream) {
    // setup_inputs order: x, T, W_ih, W_hh, b_ih, b_hh, W_fc, b_fc
    const float* x    = (const float*)d_in[0];
    const float* W_ih = (const float*)d_in[2];
    const float* W_hh = (const float*)d_in[3];
    const float* b_ih = (const float*)d_in[4];
    const float* b_hh = (const float*)d_in[5];
    const float* W_fc = (const float*)d_in[6];
    const float* b_fc = (const float*)d_in[7];
    float* out = (float*)d_out;

    const int B = in_sizes[0] / INPUT_DIM;   // 262144, divisible by BLOCK
    const int grid = B / BLOCK;              // 1024 blocks

    rnn_kernel<<<grid, BLOCK, 0, stream>>>(x, W_ih, W_hh, b_ih, b_hh,
                                           W_fc, b_fc, out);
}

// Round 2
// 139.083 us; speedup vs baseline: 5.7685x; 5.7685x over previous
//
#include <hip/hip_runtime.h>

// Elman RNN, B=262144, IN=32, H=16, T=30, OUT=1, fp32 in/out.
// Round 2: MFMA 16x16x16_bf16 with TRANSPOSED state.
//   S = H^T; step: S' = tanh(Xp^T + W_hh * S).
//   B-fragment layout == C/D-fragment layout for 16x16x16 MFMA, so the
//   fp32 accumulator (after tanh) converts elementwise to bf16 and feeds
//   straight back as the next B operand — no cross-lane transpose.
//   W_hh lives in 2 VGPRs/lane as the A-fragment (kills round-1's
//   per-iteration s_load storm: SGPR=112, 37 cyc/instr from scalar-cache
//   latency with only 2.5 waves/SIMD to hide it).
// Precision: split-bf16 emulated fp32 matmul, 3 MFMAs/step:
//   W*h ~= Whi*hhi + Whi*hlo + Wlo*hhi   (lo*lo term ~2^-16, dropped)
// xproj and fc head computed in exact fp32 VALU.

#define T_STEPS 30
#define BLOCK   256

typedef short v4s __attribute__((ext_vector_type(4)));
typedef float v4f __attribute__((ext_vector_type(4)));

__device__ __forceinline__ float tanh_fast(float v) {
    // tanh(v) = 1 - 2/(exp2(2*log2e*v)+1); exact saturation at +-inf.
    float e = __builtin_amdgcn_exp2f(v * 2.8853900817779268f);
    float r = __builtin_amdgcn_rcpf(1.0f + e);
    return fmaf(-2.0f, r, 1.0f);
}

// Truncate fp32 -> bf16 (toward zero); residual is exact in fp32.
__device__ __forceinline__ short bf16_trunc(float f) {
    return (short)(unsigned short)(__float_as_uint(f) >> 16);
}
__device__ __forceinline__ float bf16_trunc_f32(float f) {
    return __uint_as_float(__float_as_uint(f) & 0xFFFF0000u);
}

__global__ __launch_bounds__(BLOCK, 8) void rnn_mfma(
    const float* __restrict__ x,     // [B, 32]
    const float* __restrict__ W_ih,  // [16, 32]
    const float* __restrict__ W_hh,  // [16, 16]
    const float* __restrict__ b_ih,  // [16]
    const float* __restrict__ b_hh,  // [16]
    const float* __restrict__ W_fc,  // [1, 16]
    const float* __restrict__ b_fc,  // [1]
    float* __restrict__ out)         // [B, 30]
{
    __shared__ float tmp[64 * T_STEPS];   // 64 rows/block x 30 steps

    const int tid  = threadIdx.x;
    const int w    = tid >> 6;        // wave id in block (0..3), 16 rows each
    const int lane = tid & 63;
    const int r    = lane & 15;       // batch row within this wave's 16-row tile
    const int q    = lane >> 4;       // quad: this lane owns units j = 4q..4q+3

    const size_t row = (size_t)blockIdx.x * 64 + (size_t)w * 16 + r;

    // ---- xproj (exact fp32): xp[i] = b_ih[j]+b_hh[j] + dot(x[row], W_ih[j]), j=4q+i
    // Laid out directly in MFMA C-fragment order: lane holds rows j=4q+i, col r.
    const int j0 = 4 * q;
    float xp0 = b_ih[j0 + 0] + b_hh[j0 + 0];
    float xp1 = b_ih[j0 + 1] + b_hh[j0 + 1];
    float xp2 = b_ih[j0 + 2] + b_hh[j0 + 2];
    float xp3 = b_ih[j0 + 3] + b_hh[j0 + 3];
    {
        const float4* xrow = (const float4*)(x + row * 32);
#pragma unroll
        for (int c4 = 0; c4 < 8; ++c4) {
            float4 xv = xrow[c4];
            const float4 w0 = *(const float4*)(W_ih + (j0 + 0) * 32 + c4 * 4);
            const float4 w1 = *(const float4*)(W_ih + (j0 + 1) * 32 + c4 * 4);
            const float4 w2 = *(const float4*)(W_ih + (j0 + 2) * 32 + c4 * 4);
            const float4 w3 = *(const float4*)(W_ih + (j0 + 3) * 32 + c4 * 4);
            xp0 = fmaf(w0.x, xv.x, fmaf(w0.y, xv.y, fmaf(w0.z, xv.z, fmaf(w0.w, xv.w, xp0))));
            xp1 = fmaf(w1.x, xv.x, fmaf(w1.y, xv.y, fmaf(w1.z, xv.z, fmaf(w1.w, xv.w, xp1))));
            xp2 = fmaf(w2.x, xv.x, fmaf(w2.y, xv.y, fmaf(w2.z, xv.z, fmaf(w2.w, xv.w, xp2))));
            xp3 = fmaf(w3.x, xv.x, fmaf(w3.y, xv.y, fmaf(w3.z, xv.z, fmaf(w3.w, xv.w, xp3))));
        }
    }
    v4f xpv = {xp0, xp1, xp2, xp3};

    // ---- W_hh A-fragment: lane holds A[m = r][k = 4q+i] = W_hh[r][4q+i]
    // (A operand of W*S: m = output unit, k = input unit; A[m][k], m=lane&15.)
    float4 wrow = *(const float4*)(W_hh + r * 16 + 4 * q);
    v4s whi, wlo;
    {
        float wf[4] = {wrow.x, wrow.y, wrow.z, wrow.w};
#pragma unroll
        for (int i = 0; i < 4; ++i) {
            whi[i] = bf16_trunc(wf[i]);
            float lo = wf[i] - bf16_trunc_f32(wf[i]);
            wlo[i] = bf16_trunc(lo);
        }
    }

    // ---- fc weights for this lane's units
    const float4 wfc4 = *(const float4*)(W_fc + 4 * q);
    const float  bfc  = b_fc[0];

    // ---- state S = H^T in bf16 hi/lo, B-fragment == C/D-fragment layout
    v4s s_hi = {0, 0, 0, 0};
    v4s s_lo = {0, 0, 0, 0};

    for (int t = 0; t < T_STEPS; ++t) {
        // preact = Xp^T + W*S  (split-bf16 fp32 emulation)
        v4f acc = __builtin_amdgcn_mfma_f32_16x16x16bf16_1k(whi, s_hi, xpv, 0, 0, 0);
        acc = __builtin_amdgcn_mfma_f32_16x16x16bf16_1k(whi, s_lo, acc, 0, 0, 0);
        acc = __builtin_amdgcn_mfma_f32_16x16x16bf16_1k(wlo, s_hi, acc, 0, 0, 0);

        // tanh, re-split to bf16 hi/lo, fc partial — all elementwise (layout-safe)
        float partial = 0.0f;
        const float wf[4] = {wfc4.x, wfc4.y, wfc4.z, wfc4.w};
#pragma unroll
        for (int i = 0; i < 4; ++i) {
            float h = tanh_fast(acc[i]);
            s_hi[i] = bf16_trunc(h);
            float lo = h - bf16_trunc_f32(h);
            s_lo[i] = bf16_trunc(lo);
            partial = fmaf(h, wf[i], partial);
        }

        // reduce over the 4 quads (lanes r, r+16, r+32, r+48): all lanes end with full sum
        partial += __shfl_xor(partial, 16);
        partial += __shfl_xor(partial, 32);

        if (lane < 16)
            tmp[(w * 16 + lane) * T_STEPS + t] = partial + bfc;
    }

    __syncthreads();

    // ---- coalesced writeout: block's region out[block*64 .. +64][0..30) is contiguous
    float* oblk = out + (size_t)blockIdx.x * (64 * T_STEPS);
    for (int idx = tid; idx < 64 * T_STEPS; idx += BLOCK)
        oblk[idx] = tmp[idx];
}

extern "C" void kernel_launch(void* const* d_in, const int* in_sizes, int n_in,
                              void* d_out, int out_size, void* d_ws, size_t ws_size,
                              hipStream_t stream) {
    // inputs: x, T, W_ih, W_hh, b_ih, b_hh, W_fc, b_fc
    const float* x    = (const float*)d_in[0];
    const float* W_ih = (const float*)d_in[2];
    const float* W_hh = (const float*)d_in[3];
    const float* b_ih = (const float*)d_in[4];
    const float* b_hh = (const float*)d_in[5];
    const float* W_fc = (const float*)d_in[6];
    const float* b_fc = (const float*)d_in[7];
    float* out = (float*)d_out;

    const int B = in_sizes[0] / 32;      // 262144
    const int grid = B / 64;             // 4096 blocks, 64 rows each

    rnn_mfma<<<grid, BLOCK, 0, stream>>>(x, W_ih, W_hh, b_ih, b_hh, W_fc, b_fc, out);
}

// Round 3
// 138.622 us; speedup vs baseline: 5.7877x; 1.0033x over previous
//
#include <hip/hip_runtime.h>

// Elman RNN, B=262144, IN=32, H=16, T=30, OUT=1, fp32 in/out.
// Round 3 (from round-2 MFMA version, 65 us dispatch):
//  - fc head via 2 extra MFMAs (A rows: row0=bf16hi(W_fc), row1=bf16lo(W_fc))
//    -> o = facc[0]+facc[1] in lanes 0..15; kills 2 dependent shfl(DS) ops
//    per step in the serial t-chain. MFMA pipe had 85% headroom.
//  - split-bf16 state repack via v_perm_b32 (1 op packs 2 bf16-hi), 12 VALU.
//  - t-loop fully unrolled: LDS store addr = base + immediate, no per-step
//    address arithmetic / branch.
// State stays transposed (S = H^T): B-frag layout == C/D-frag layout for
// 16x16x16 MFMA, so tanh(acc) re-packs elementwise into the next B operand.

#define T_STEPS 30
#define BLOCK   256

typedef short v4s __attribute__((ext_vector_type(4)));
typedef float v4f __attribute__((ext_vector_type(4)));
typedef int   v2i __attribute__((ext_vector_type(2)));

__device__ __forceinline__ float tanh_fast(float v) {
    // tanh(v) = 1 - 2/(exp2(2*log2e*v)+1); exact saturation at +-inf.
    float e = __builtin_amdgcn_exp2f(v * 2.8853900817779268f);
    float r = __builtin_amdgcn_rcpf(1.0f + e);
    return fmaf(-2.0f, r, 1.0f);
}

// One dword: low short = bf16_trunc(a), high short = bf16_trunc(b).
// {src0=b(hi),src1=a(lo)} bytes: D = [b.b3, b.b2, a.b3, a.b2] -> sel 0x07060302
__device__ __forceinline__ int pack_bf16hi(float a, float b) {
    return (int)__builtin_amdgcn_perm(__float_as_uint(b), __float_as_uint(a),
                                      0x07060302u);
}

__device__ __forceinline__ v4s pack4(float a, float b, float c, float d) {
    v2i p;
    p[0] = pack_bf16hi(a, b);
    p[1] = pack_bf16hi(c, d);
    return __builtin_bit_cast(v4s, p);
}

__device__ __forceinline__ float bf16_trunc_f32(float f) {
    return __uint_as_float(__float_as_uint(f) & 0xFFFF0000u);
}

__global__ __launch_bounds__(BLOCK, 8) void rnn_mfma(
    const float* __restrict__ x,     // [B, 32]
    const float* __restrict__ W_ih,  // [16, 32]
    const float* __restrict__ W_hh,  // [16, 16]
    const float* __restrict__ b_ih,  // [16]
    const float* __restrict__ b_hh,  // [16]
    const float* __restrict__ W_fc,  // [1, 16]
    const float* __restrict__ b_fc,  // [1]
    float* __restrict__ out)         // [B, 30]
{
    __shared__ float tmp[64 * T_STEPS];   // 64 rows/block x 30 steps

    const int tid  = threadIdx.x;
    const int w    = tid >> 6;        // wave in block (0..3), 16 rows each
    const int lane = tid & 63;
    const int r    = lane & 15;       // MFMA row index (batch row / A-row)
    const int q    = lane >> 4;       // quad

    const size_t row = (size_t)blockIdx.x * 64 + (size_t)w * 16 + r;

    // ---- xproj (exact fp32), laid out in MFMA C-fragment order:
    // lane holds rows j = 4q+i, col r.
    const int j0 = 4 * q;
    float xp0 = b_ih[j0 + 0] + b_hh[j0 + 0];
    float xp1 = b_ih[j0 + 1] + b_hh[j0 + 1];
    float xp2 = b_ih[j0 + 2] + b_hh[j0 + 2];
    float xp3 = b_ih[j0 + 3] + b_hh[j0 + 3];
    {
        const float4* xrow = (const float4*)(x + row * 32);
#pragma unroll
        for (int c4 = 0; c4 < 8; ++c4) {
            float4 xv = xrow[c4];
            const float4 w0 = *(const float4*)(W_ih + (j0 + 0) * 32 + c4 * 4);
            const float4 w1 = *(const float4*)(W_ih + (j0 + 1) * 32 + c4 * 4);
            const float4 w2 = *(const float4*)(W_ih + (j0 + 2) * 32 + c4 * 4);
            const float4 w3 = *(const float4*)(W_ih + (j0 + 3) * 32 + c4 * 4);
            xp0 = fmaf(w0.x, xv.x, fmaf(w0.y, xv.y, fmaf(w0.z, xv.z, fmaf(w0.w, xv.w, xp0))));
            xp1 = fmaf(w1.x, xv.x, fmaf(w1.y, xv.y, fmaf(w1.z, xv.z, fmaf(w1.w, xv.w, xp1))));
            xp2 = fmaf(w2.x, xv.x, fmaf(w2.y, xv.y, fmaf(w2.z, xv.z, fmaf(w2.w, xv.w, xp2))));
            xp3 = fmaf(w3.x, xv.x, fmaf(w3.y, xv.y, fmaf(w3.z, xv.z, fmaf(w3.w, xv.w, xp3))));
        }
    }
    const v4f xpv = {xp0, xp1, xp2, xp3};

    // ---- W_hh A-fragment: A[m=r][k=4q+i] = W_hh[r][4q+i], split hi/lo
    v4s whi, wlo;
    {
        float4 wr = *(const float4*)(W_hh + r * 16 + 4 * q);
        float wf[4] = {wr.x, wr.y, wr.z, wr.w};
        whi = pack4(wf[0], wf[1], wf[2], wf[3]);
        wlo = pack4(wf[0] - bf16_trunc_f32(wf[0]), wf[1] - bf16_trunc_f32(wf[1]),
                    wf[2] - bf16_trunc_f32(wf[2]), wf[3] - bf16_trunc_f32(wf[3]));
    }

    // ---- fc A-fragment: row0 = bf16hi(W_fc), row1 = bf16lo(W_fc), rest 0
    v4s afc;
    {
        float f[4];
#pragma unroll
        for (int i = 0; i < 4; ++i) {
            float wv = W_fc[4 * q + i];
            float lo = wv - bf16_trunc_f32(wv);
            f[i] = (r == 0) ? wv : ((r == 1) ? lo : 0.0f);
        }
        afc = pack4(f[0], f[1], f[2], f[3]);
    }

    // fc C init: bias lands in row 0 (q==0, reg 0)
    const float bfc = b_fc[0];
    const v4f zfc = {(q == 0) ? bfc : 0.0f, 0.0f, 0.0f, 0.0f};

    // ---- state S = H^T in bf16 hi/lo (B-frag == C/D-frag layout)
    v4s s_hi = {0, 0, 0, 0};
    v4s s_lo = {0, 0, 0, 0};

    float* myout = &tmp[(w * 16 + r) * T_STEPS];   // lanes 0..15 write

#pragma unroll
    for (int t = 0; t < T_STEPS; ++t) {
        // preact = Xp^T + W*S  (split-bf16 fp32 emulation, 3 MFMAs)
        v4f acc = __builtin_amdgcn_mfma_f32_16x16x16bf16_1k(whi, s_hi, xpv, 0, 0, 0);
        acc = __builtin_amdgcn_mfma_f32_16x16x16bf16_1k(whi, s_lo, acc, 0, 0, 0);
        acc = __builtin_amdgcn_mfma_f32_16x16x16bf16_1k(wlo, s_hi, acc, 0, 0, 0);

        // tanh + re-split (elementwise, layout-safe)
        float h0 = tanh_fast(acc[0]);
        float h1 = tanh_fast(acc[1]);
        float h2 = tanh_fast(acc[2]);
        float h3 = tanh_fast(acc[3]);
        s_hi = pack4(h0, h1, h2, h3);
        s_lo = pack4(h0 - bf16_trunc_f32(h0), h1 - bf16_trunc_f32(h1),
                     h2 - bf16_trunc_f32(h2), h3 - bf16_trunc_f32(h3));

        // fc head: o = (wfc_hi+wfc_lo) . (s_hi+s_lo) + bfc, rows 0+1
        v4f facc = __builtin_amdgcn_mfma_f32_16x16x16bf16_1k(afc, s_hi, zfc, 0, 0, 0);
        facc = __builtin_amdgcn_mfma_f32_16x16x16bf16_1k(afc, s_lo, facc, 0, 0, 0);

        if (lane < 16)
            myout[t] = facc[0] + facc[1];
    }

    __syncthreads();

    // ---- coalesced writeout: block region out[block*64..+64)[0..30) contiguous
    float* oblk = out + (size_t)blockIdx.x * (64 * T_STEPS);
    for (int idx = tid; idx < 64 * T_STEPS; idx += BLOCK)
        oblk[idx] = tmp[idx];
}

extern "C" void kernel_launch(void* const* d_in, const int* in_sizes, int n_in,
                              void* d_out, int out_size, void* d_ws, size_t ws_size,
                              hipStream_t stream) {
    // inputs: x, T, W_ih, W_hh, b_ih, b_hh, W_fc, b_fc
    const float* x    = (const float*)d_in[0];
    const float* W_ih = (const float*)d_in[2];
    const float* W_hh = (const float*)d_in[3];
    const float* b_ih = (const float*)d_in[4];
    const float* b_hh = (const float*)d_in[5];
    const float* W_fc = (const float*)d_in[6];
    const float* b_fc = (const float*)d_in[7];
    float* out = (float*)d_out;

    const int B = in_sizes[0] / 32;      // 262144
    const int grid = B / 64;             // 4096 blocks, 64 rows each

    rnn_mfma<<<grid, BLOCK, 0, stream>>>(x, W_ih, W_hh, b_ih, b_hh, W_fc, b_fc, out);
}